// Round 2
// baseline (309.125 us; speedup 1.0000x reference)
//
#include <hip/hip_runtime.h>
#include <hip/hip_bf16.h>

typedef __bf16 bf16;
typedef __bf16 bf16x4 __attribute__((ext_vector_type(4)));
typedef __bf16 bf16x8 __attribute__((ext_vector_type(8)));
typedef float  f32x4  __attribute__((ext_vector_type(4)));

#define AS1 __attribute__((address_space(1)))
#define AS3 __attribute__((address_space(3)))

__device__ __forceinline__ void gload_lds16(const bf16* g, bf16* l) {
    __builtin_amdgcn_global_load_lds((const AS1 void*)g, (AS3 void*)l, 16, 0, 0);
}

__device__ __forceinline__ void stage8_f32(const float* s, bf16* l) {
    float4 a = *(const float4*)s;
    float4 b = *(const float4*)(s + 4);
    bf16x8 o;
    o[0] = (bf16)a.x; o[1] = (bf16)a.y; o[2] = (bf16)a.z; o[3] = (bf16)a.w;
    o[4] = (bf16)b.x; o[5] = (bf16)b.y; o[6] = (bf16)b.z; o[7] = (bf16)b.w;
    *(bf16x8*)l = o;
}

// ---------------------------------------------------------------------------
// 128x128 GEMM tile core: acc += A[M,K] @ B[N,K]^T (bf16 MFMA).
// v2: 2-phase double-buffered staging (prefetch next K-tile before compute,
// single vmcnt/lgkm drain + raw s_barrier per K-step). At this problem's
// shapes grid is ~1 block/CU (1 wave/SIMD), so there is no inter-block
// overlap to hide the staging latency -- explicit pipelining is required.
// ---------------------------------------------------------------------------
template <bool AF32, bool BF32>
__device__ __forceinline__ void gemm_core(
    const void* __restrict__ Av, const void* __restrict__ Bv,
    int m0, int n0, int K, f32x4 (&acc)[4][4],
    int wm, int wn, int r16, int q8)
{
    constexpr int LDA = AF32 ? 40 : 32;
    constexpr int LDB = BF32 ? 40 : 32;
    __shared__ __align__(16) bf16 As[2][128 * LDA];
    __shared__ __align__(16) bf16 Bs[2][128 * LDB];

    const int tid = threadIdx.x;
    const int i0 = tid, i1 = tid + 256;
    const int r0 = i0 >> 2, c0 = (i0 & 3) * 8;
    const int r1 = i1 >> 2, c1 = (i1 & 3) * 8;
    const size_t a0 = (size_t)(m0 + r0) * K + c0, a1 = (size_t)(m0 + r1) * K + c1;
    const size_t b0 = (size_t)(n0 + r0) * K + c0, b1 = (size_t)(n0 + r1) * K + c1;

    auto stage = [&](int buf, int k0) {
        if constexpr (AF32) {
            stage8_f32((const float*)Av + a0 + k0, &As[buf][r0 * LDA + c0]);
            stage8_f32((const float*)Av + a1 + k0, &As[buf][r1 * LDA + c1]);
        } else {
            gload_lds16((const bf16*)Av + a0 + k0, &As[buf][i0 * 8]);
            gload_lds16((const bf16*)Av + a1 + k0, &As[buf][i1 * 8]);
        }
        if constexpr (BF32) {
            stage8_f32((const float*)Bv + b0 + k0, &Bs[buf][r0 * LDB + c0]);
            stage8_f32((const float*)Bv + b1 + k0, &Bs[buf][r1 * LDB + c1]);
        } else {
            gload_lds16((const bf16*)Bv + b0 + k0, &Bs[buf][i0 * 8]);
            gload_lds16((const bf16*)Bv + b1 + k0, &Bs[buf][i1 * 8]);
        }
    };

    // prologue: stage tile 0 into buf 0 (syncthreads drains vmcnt+lgkm)
    stage(0, 0);
    __syncthreads();

    int cur = 0;
    for (int k0 = 0; k0 < K; k0 += 32) {
        // issue next-tile prefetch into the other buffer BEFORE compute;
        // its latency hides under the 8 ds_reads + 16 MFMAs below.
        if (k0 + 32 < K) stage(cur ^ 1, k0 + 32);

        bf16x8 a[4], b[4];
#pragma unroll
        for (int r = 0; r < 4; ++r)
            a[r] = *(const bf16x8*)&As[cur][(wm + r * 16 + r16) * LDA + q8 * 8];
#pragma unroll
        for (int c = 0; c < 4; ++c)
            b[c] = *(const bf16x8*)&Bs[cur][(wn + c * 16 + r16) * LDB + q8 * 8];
#pragma unroll
        for (int r = 0; r < 4; ++r)
#pragma unroll
            for (int c = 0; c < 4; ++c)
                acc[r][c] = __builtin_amdgcn_mfma_f32_16x16x32_bf16(a[r], b[c], acc[r][c], 0, 0, 0);

        // publish buf[cur^1]: prefetch landed (vmcnt) and this wave's reads
        // of buf[cur] drained (lgkm) -> safe to overwrite buf[cur] next iter.
        asm volatile("s_waitcnt vmcnt(0) lgkmcnt(0)" ::: "memory");
        __builtin_amdgcn_s_barrier();
        __builtin_amdgcn_sched_barrier(0);
        cur ^= 1;
    }
}

// fp32 -> bf16 bulk convert: y selects {x, Wq, Wlk, Wlv, Wo}.
__global__ __launch_bounds__(256) void cvt5(
    const float* __restrict__ s0, const float* __restrict__ s1,
    const float* __restrict__ s2, const float* __restrict__ s3,
    const float* __restrict__ s4,
    bf16* __restrict__ d0, bf16* __restrict__ d1, bf16* __restrict__ d2,
    bf16* __restrict__ d3, bf16* __restrict__ d4)
{
    const float* S[5] = {s0, s1, s2, s3, s4};
    bf16*        D[5] = {d0, d1, d2, d3, d4};
    const int    N[5] = {4194304, 4194304, 1048576, 1048576, 4194304};
    int y = blockIdx.y;
    int base = (blockIdx.x * 256 + threadIdx.x) * 8;
    if (base >= N[y]) return;
    stage8_f32(S[y] + base, D[y] + base);
}

// ---------------------------------------------------------------------------
// Projections: grid=(24,16); bx<16 -> Q, 16..19 -> LK, 20..23 -> LV stored
// TRANSPOSED as LVt[hd=512][T=2048] (b64-packed epilogue).
// ---------------------------------------------------------------------------
template <bool F32>
__global__ __launch_bounds__(256) void proj_kernel_t(
    const void* __restrict__ x, const void* __restrict__ Wq,
    const void* __restrict__ Wlk, const void* __restrict__ Wlv,
    bf16* __restrict__ Q, bf16* __restrict__ LK, bf16* __restrict__ LVt)
{
    const int bx = blockIdx.x, by = blockIdx.y;
    const int tid = threadIdx.x, lane = tid & 63, wave = tid >> 6;
    const int wm = (wave >> 1) * 64, wn = (wave & 1) * 64;
    const int r16 = lane & 15, q8 = lane >> 4;
    f32x4 acc[4][4] = {};

    const void* Bv; int n0;
    if (bx < 16)      { Bv = Wq;  n0 = bx * 128; }
    else if (bx < 20) { Bv = Wlk; n0 = (bx - 16) * 128; }
    else              { Bv = Wlv; n0 = (bx - 20) * 128; }

    gemm_core<F32, F32>(x, Bv, by * 128, n0, 2048, acc, wm, wn, r16, q8);

    if (bx < 20) {
        bf16* C  = (bx < 16) ? Q : LK;
        int ldc  = (bx < 16) ? 2048 : 512;
#pragma unroll
        for (int r = 0; r < 4; ++r)
#pragma unroll
            for (int c = 0; c < 4; ++c)
#pragma unroll
                for (int i = 0; i < 4; ++i) {
                    int row = by * 128 + wm + r * 16 + q8 * 4 + i;
                    int col = n0 + wn + c * 16 + r16;
                    C[(size_t)row * ldc + col] = (bf16)acc[r][c][i];
                }
    } else {
#pragma unroll
        for (int r = 0; r < 4; ++r)
#pragma unroll
            for (int c = 0; c < 4; ++c) {
                int hd = n0 + wn + c * 16 + r16;
                int tb = by * 128 + wm + r * 16 + q8 * 4;
                bf16x4 pk;
#pragma unroll
                for (int i = 0; i < 4; ++i) pk[i] = (bf16)acc[r][c][i];
                *(bf16x4*)&LVt[(size_t)hd * 2048 + tb] = pk;
            }
    }
}

// Output GEMM: out = ATT(bf16) @ Wo^T -> fp32 d_out. grid=(16,16).
template <bool BF32>
__global__ __launch_bounds__(256) void out_kernel_t(
    const bf16* __restrict__ A, const void* __restrict__ Wo, float* __restrict__ C)
{
    const int tid = threadIdx.x, lane = tid & 63, wave = tid >> 6;
    const int wm = (wave >> 1) * 64, wn = (wave & 1) * 64;
    const int r16 = lane & 15, q8 = lane >> 4;
    f32x4 acc[4][4] = {};
    gemm_core<false, BF32>(A, Wo, blockIdx.y * 128, blockIdx.x * 128, 2048, acc, wm, wn, r16, q8);
#pragma unroll
    for (int r = 0; r < 4; ++r)
#pragma unroll
        for (int c = 0; c < 4; ++c)
#pragma unroll
            for (int i = 0; i < 4; ++i) {
                int row = blockIdx.y * 128 + wm + r * 16 + q8 * 4 + i;
                int col = blockIdx.x * 128 + wn + c * 16 + r16;
                C[(size_t)row * 2048 + col] = acc[r][c][i];
            }
}

// ---------------------------------------------------------------------------
// Attention v4: t-block 128 (2 strips/wave, 2x MFMA per staged tile) +
// double-buffered K/V staging with raw-barrier 2-phase schedule (prefetch
// issued before compute; single vmcnt/lgkm drain + s_barrier per iter).
// grid=(16,64): x = 128-row t block, y = h*4+g. S^T = K*Q^T.
// ---------------------------------------------------------------------------
__global__ __launch_bounds__(256) void attn4(
    const bf16* __restrict__ Q, const bf16* __restrict__ LK,
    const bf16* __restrict__ LVt, bf16* __restrict__ O)
{
    __shared__ __align__(16) bf16 Ks[2][64 * 32];   // [s][d], chunk q^((row>>1)&3)
    __shared__ __align__(16) bf16 Vs[2][32 * 64];   // [d][s], chunk q^(row&7)
    __shared__ __align__(16) bf16 Ps[64 * 72];      // [t][s], LD=72, wave-private

    const int tid  = threadIdx.x;
    const int lane = tid & 63;
    const int w    = tid >> 6;
    const int r16  = lane & 15;
    const int q8   = lane >> 4;
    const int hg = blockIdx.y, h = hg >> 2, g = hg & 3;
    const int t0 = blockIdx.x * 128;

    // loop-invariant Q B-fragments, one per 16-row strip: B[n=t][k=d]
    bf16x8 qb[2];
#pragma unroll
    for (int p = 0; p < 2; ++p)
        qb[p] = *(const bf16x8*)(Q + (size_t)(t0 + w * 32 + p * 16 + r16) * 2048
                                 + h * 128 + g * 32 + q8 * 8);

    // K staging: thread -> local row kr=tid>>2, swizzled global chunk
    const int kr = tid >> 2;
    const int kq = (tid & 3) ^ ((tid >> 3) & 3);
    const bf16* kg = LK + (size_t)kr * 512 + h * 32 + kq * 8;
    // V staging: local row vd=tid>>3, swizzled global chunk (row 128B coalesced)
    const int vd = tid >> 3;
    const int vq = (tid & 7) ^ ((tid >> 3) & 7);
    const bf16* vg = LVt + (size_t)(h * 32 + vd) * 2048 + vq * 8;

    const int ksw = (r16 >> 1) & 3;   // K read swizzle
    const int vsw = r16 & 7;          // V read swizzle

    f32x4 o_acc[2][2] = {};
    float lsum[2] = {0.f, 0.f};
    const float Cc = 0.08838834764831845f * 1.4426950408889634f;  // 1/sqrt(128)*log2(e)
    const f32x4 z = {0.f, 0.f, 0.f, 0.f};

    // prologue: stage tile 0 into buf 0 (syncthreads drains vmcnt)
    gload_lds16(kg, &Ks[0][tid * 8]);
    gload_lds16(vg, &Vs[0][tid * 8]);
    __syncthreads();

    int cur = 0;
    for (int sb = 0; sb < 2048; sb += 64) {
        // issue next-tile prefetch into the other buffer BEFORE compute;
        // its latency hides under 16 MFMAs + softmax below.
        if (sb + 64 < 2048) {
            gload_lds16(kg + (size_t)(sb + 64) * 512, &Ks[cur ^ 1][tid * 8]);
            gload_lds16(vg + (sb + 64),               &Vs[cur ^ 1][tid * 8]);
        }
        const bf16* ks = Ks[cur];
        const bf16* vs = Vs[cur];

#pragma unroll
        for (int p = 0; p < 2; ++p) {
            // S^T tile: A = K rows (m=s), B = Q strip p (n=t)
            f32x4 s[4];
            __builtin_amdgcn_s_setprio(1);
#pragma unroll
            for (int c = 0; c < 4; ++c) {
                bf16x8 kb = *(const bf16x8*)&ks[(c * 16 + r16) * 32 + (q8 ^ ksw) * 8];
                s[c] = __builtin_amdgcn_mfma_f32_16x16x32_bf16(kb, qb[p], z, 0, 0, 0);
            }
            __builtin_amdgcn_s_setprio(0);
            // lane holds S[t=w*32+p*16+r16][s=c*16+q8*4+i] -> exp -> packed b64
#pragma unroll
            for (int c = 0; c < 4; ++c) {
                bf16x4 pk;
#pragma unroll
                for (int i = 0; i < 4; ++i) {
                    float pv = exp2f(s[c][i] * Cc);
                    lsum[p] += pv;
                    pk[i] = (bf16)pv;
                }
                *(bf16x4*)&Ps[(w * 16 + r16) * 72 + c * 16 + q8 * 4] = pk;
            }
            // O += P @ V^T : A = P (wave-private strip), B = Vs rows (n=d)
            __builtin_amdgcn_s_setprio(1);
#pragma unroll
            for (int kk = 0; kk < 2; ++kk) {
                bf16x8 ap = *(const bf16x8*)&Ps[(w * 16 + r16) * 72 + kk * 32 + q8 * 8];
#pragma unroll
                for (int ct = 0; ct < 2; ++ct) {
                    bf16x8 vb = *(const bf16x8*)&vs[(ct * 16 + r16) * 64
                                                    + (((kk * 4 + q8) ^ vsw) * 8)];
                    o_acc[p][ct] = __builtin_amdgcn_mfma_f32_16x16x32_bf16(ap, vb, o_acc[p][ct], 0, 0, 0);
                }
            }
            __builtin_amdgcn_s_setprio(0);
        }

        // publish buf[cur^1]: prefetch landed (vmcnt) and this wave's reads of
        // buf[cur] are drained (lgkm) -> safe to overwrite buf[cur] next iter.
        asm volatile("s_waitcnt vmcnt(0) lgkmcnt(0)" ::: "memory");
        __builtin_amdgcn_s_barrier();
        __builtin_amdgcn_sched_barrier(0);
        cur ^= 1;
    }

    // per strip: row-sum for t = w*32+p*16+r16 (reduce over q8 groups), then
    // redistribute to C-layout rows t_local = q8*4+i
#pragma unroll
    for (int p = 0; p < 2; ++p) {
        float l = lsum[p];
        l += __shfl_xor(l, 16);
        l += __shfl_xor(l, 32);
        float ls[4];
#pragma unroll
        for (int i = 0; i < 4; ++i) ls[i] = __shfl(l, q8 * 4 + i);
#pragma unroll
        for (int ct = 0; ct < 2; ++ct)
#pragma unroll
            for (int i = 0; i < 4; ++i) {
                float o = o_acc[p][ct][i] / ls[i];
                int t = t0 + w * 32 + p * 16 + q8 * 4 + i;
                int d = ct * 16 + r16;
                O[(size_t)t * 2048 + h * 128 + g * 32 + d] = (bf16)o;
            }
    }
}

// ---------------------------------------------------------------------------
// Contract (verified R6 bench): inputs fp32, output fp32.
// ---------------------------------------------------------------------------
extern "C" void kernel_launch(void* const* d_in, const int* in_sizes, int n_in,
                              void* d_out, int out_size, void* d_ws, size_t ws_size,
                              hipStream_t stream) {
    const float* x   = (const float*)d_in[0];
    const float* Wq  = (const float*)d_in[1];
    // d_in[2]=Wk, d_in[3]=Wv: computed-but-unused in the reference -> skipped
    const float* Wlk = (const float*)d_in[4];
    const float* Wlv = (const float*)d_in[5];
    const float* Wo  = (const float*)d_in[6];
    float* out = (float*)d_out;

    const size_t M4 = 4194304, M1 = 1048576;
    const size_t need_fast = (M1 + M1 + M4 + M4 + M1 + M1) * 2;  // 24 MB

    if (ws_size >= need_fast) {
        bf16* xb   = (bf16*)d_out;      // d_out scratch: dead before out_kernel writes
        bf16* Wqb  = xb + M4;
        bf16* p    = (bf16*)d_ws;
        bf16* Wlkb = p; p += M1;
        bf16* Wlvb = p; p += M1;
        bf16* Wob  = p; p += M4;
        bf16* Qp   = p; p += M4;
        bf16* LKp  = p; p += M1;
        bf16* LVt  = p;
        bf16* ATT  = Qp;                // alias: attn block reads its own Q cells first

        cvt5<<<dim3(2048, 5), 256, 0, stream>>>(x, Wq, Wlk, Wlv, Wo,
                                                xb, Wqb, Wlkb, Wlvb, Wob);
        proj_kernel_t<false><<<dim3(24, 16), 256, 0, stream>>>(xb, Wqb, Wlkb, Wlvb,
                                                               Qp, LKp, LVt);
        attn4<<<dim3(16, 64), 256, 0, stream>>>(Qp, LKp, LVt, ATT);
        out_kernel_t<false><<<dim3(16, 16), 256, 0, stream>>>(ATT, Wob, out);
    } else {
        bf16* Qp  = (bf16*)d_ws;
        bf16* LKp = Qp + M4;
        bf16* LVt = LKp + M1;
        bf16* ATT = Qp;

        proj_kernel_t<true><<<dim3(24, 16), 256, 0, stream>>>(x, Wq, Wlk, Wlv,
                                                              Qp, LKp, LVt);
        attn4<<<dim3(16, 64), 256, 0, stream>>>(Qp, LKp, LVt, ATT);
        out_kernel_t<true><<<dim3(16, 16), 256, 0, stream>>>(ATT, Wo, out);
    }
}